// Round 4
// baseline (1164.177 us; speedup 1.0000x reference)
//
#include <hip/hip_runtime.h>
#include <stdint.h>

#define T_LEN 2048
#define RAD   32

typedef unsigned short ushort_t;

__device__ __forceinline__ unsigned short f2bf(float f) {
  union { float f; unsigned int u; } v; v.f = f;
  unsigned int u = v.u;
  return (unsigned short)((u + 0x7FFFu + ((u >> 16) & 1u)) >> 16);
}
__device__ __forceinline__ float bf2f(unsigned short u) {
  union { unsigned int u; float f; } v; v.u = ((unsigned int)u) << 16;
  return v.f;
}

// ---------------- simple fp32 GEMM 1: C_bf16[M][N] = A_f32[M][K] * B_f32[N][K]^T + bias ----------------
__global__ __launch_bounds__(256) void gemm1_f32(
    const float* __restrict__ A, const float* __restrict__ B,
    const float* __restrict__ bias, ushort_t* __restrict__ C,
    int M, int N, int K) {
  __shared__ float As[16][17];
  __shared__ float Bs[16][17];
  const int tx = threadIdx.x, ty = threadIdx.y;
  const int row = blockIdx.y * 16 + ty;
  const int col = blockIdx.x * 16 + tx;
  const int brow = blockIdx.x * 16 + ty;
  float acc = 0.f;
  for (int kt = 0; kt < K; kt += 16) {
    As[ty][tx] = A[(size_t)row * K + kt + tx];
    Bs[ty][tx] = B[(size_t)brow * K + kt + tx];
    __syncthreads();
#pragma unroll
    for (int k = 0; k < 16; ++k) acc += As[ty][k] * Bs[tx][k];
    __syncthreads();
  }
  C[(size_t)row * N + col] = f2bf(acc + bias[col]);
}

// ---------------- simple fp32 GEMM 2: C_f32[M][N] = A_bf16[M][K] * B_f32[N][K]^T + bias ----------------
__global__ __launch_bounds__(256) void gemm2_f32(
    const ushort_t* __restrict__ A, const float* __restrict__ B,
    const float* __restrict__ bias, float* __restrict__ C,
    int M, int N, int K) {
  __shared__ float As[16][17];
  __shared__ float Bs[16][17];
  const int tx = threadIdx.x, ty = threadIdx.y;
  const int row = blockIdx.y * 16 + ty;
  const int col = blockIdx.x * 16 + tx;
  const int brow = blockIdx.x * 16 + ty;
  float acc = 0.f;
  for (int kt = 0; kt < K; kt += 16) {
    As[ty][tx] = bf2f(A[(size_t)row * K + kt + tx]);
    Bs[ty][tx] = B[(size_t)brow * K + kt + tx];
    __syncthreads();
#pragma unroll
    for (int k = 0; k < 16; ++k) acc += As[ty][k] * Bs[tx][k];
    __syncthreads();
  }
  C[(size_t)row * N + col] = acc + bias[col];
}

// ---------------- fp32 local attention, register softmax (NO Wts LDS) ----------------
// Block: 256 thr = 4 waves, (b, h, 32 queries). Weights distributed via __shfl.
__global__ __launch_bounds__(256) void attn_kernel(
    const ushort_t* __restrict__ qkv, ushort_t* __restrict__ ctx) {
  const int b = blockIdx.z, h = blockIdx.y, t0 = blockIdx.x * 32;
  __shared__ float Kt[96][65];
  __shared__ float Vt[96][64];
  __shared__ float Qt[32][64];
  const int tid = threadIdx.x;
  const size_t baseBT = (size_t)b * T_LEN;

  // scalar staging (no vector-cast assumptions)
  for (int idx = tid; idx < 96 * 64; idx += 256) {
    int row = idx >> 6, d = idx & 63;
    int t = t0 - RAD + row;
    float kv = 0.f, vv = 0.f;
    if (t >= 0 && t < T_LEN) {
      size_t base = (baseBT + t) * 1536 + h * 64 + d;
      kv = bf2f(qkv[base + 512]);
      vv = bf2f(qkv[base + 1024]);
    }
    Kt[row][d] = kv; Vt[row][d] = vv;
  }
  for (int idx = tid; idx < 32 * 64; idx += 256) {
    int row = idx >> 6, d = idx & 63;
    Qt[row][d] = bf2f(qkv[(baseBT + t0 + row) * 1536 + h * 64 + d]);
  }
  __syncthreads();

  const int wave = tid >> 6, lane = tid & 63;
  for (int qi = 0; qi < 8; ++qi) {
    const int qrow = wave * 8 + qi;
    const int t = t0 + qrow;
    // ---- phase 1: lane = window offset w (0..63) ----
    float s = 0.f;
    for (int d = 0; d < 64; ++d)
      s += Qt[qrow][d] * Kt[qrow + lane][d];
    // w = 64 tail: lanes = d, full butterfly reduce (all lanes end uniform)
    float p64 = Qt[qrow][lane] * Kt[qrow + 64][lane];
#pragma unroll
    for (int off = 32; off; off >>= 1) p64 += __shfl_xor(p64, off);

    int tw = t - RAD + lane;
    bool valid = (tw >= 0) && (tw < T_LEN);
    bool valid64 = (t + RAD) < T_LEN;
    float sv = valid ? s * 0.125f : -1e30f;
    float s64 = valid64 ? p64 * 0.125f : -1e30f;
    float mx = sv;
#pragma unroll
    for (int off = 32; off; off >>= 1) mx = fmaxf(mx, __shfl_xor(mx, off));
    mx = fmaxf(mx, s64);
    float e = valid ? expf(sv - mx) : 0.f;
    float esum = e;
#pragma unroll
    for (int off = 32; off; off >>= 1) esum += __shfl_xor(esum, off);
    float e64 = valid64 ? expf(s64 - mx) : 0.f;
    esum += e64;
    float inv = 1.0f / esum;
    float wv = e * inv;        // this lane's weight, w = lane
    float tail = e64 * inv;    // wave-uniform (p64/mx/esum uniform)

    // ---- phase 2: lane = d; weights broadcast via shuffle (race-free) ----
    float c = 0.f;
#pragma unroll
    for (int w = 0; w < 64; ++w)
      c += __shfl(wv, w) * Vt[qrow + w][lane];
    c += tail * Vt[qrow + 64][lane];

    ctx[(baseBT + t) * 512 + h * 64 + lane] = f2bf(c);
  }
}

// ---------------- launch ----------------
extern "C" void kernel_launch(void* const* d_in, const int* in_sizes, int n_in,
                              void* d_out, int out_size, void* d_ws, size_t ws_size,
                              hipStream_t stream) {
  // Bind inputs by unique element count (immune to ordering assumptions).
  const float* x = nullptr; const float* Wqkv = nullptr; const float* bqkv = nullptr;
  const float* Wout = nullptr; const float* bout = nullptr;
  for (int i = 0; i < n_in; ++i) {
    switch (in_sizes[i]) {
      case 4194304: x    = (const float*)d_in[i]; break;  // 4*2048*512
      case 786432:  Wqkv = (const float*)d_in[i]; break;  // 1536*512
      case 1536:    bqkv = (const float*)d_in[i]; break;
      case 262144:  Wout = (const float*)d_in[i]; break;  // 512*512
      case 512:     bout = (const float*)d_in[i]; break;
      default: break;
    }
  }
  const size_t need_ws = ((size_t)8192 * 1536 + (size_t)8192 * 512) * 2;  // 32 MiB
  if (!x || !Wqkv || !bqkv || !Wout || !bout || ws_size < need_ws) {
    // sentinel: leave d_out as-is (harness memset 0) -> absmax == 1.218750
    return;
  }
  float* out = (float*)d_out;

  ushort_t* qkvb = (ushort_t*)d_ws;                 // 8192*1536 bf16 = 24 MiB
  ushort_t* ctxb = qkvb + (size_t)8192 * 1536;      // 8192*512  bf16 =  8 MiB

  gemm1_f32<<<dim3(96, 512), dim3(16, 16), 0, stream>>>(
      x, Wqkv, bqkv, qkvb, 8192, 1536, 512);

  attn_kernel<<<dim3(64, 8, 4), dim3(256), 0, stream>>>(qkvb, ctxb);

  gemm2_f32<<<dim3(32, 512), dim3(16, 16), 0, stream>>>(
      ctxb, Wout, bout, out, 8192, 512, 512);
}

// Round 5
// 166.259 us; speedup vs baseline: 7.0022x; 7.0022x over previous
//
#include <hip/hip_runtime.h>
#include <stdint.h>

#define T_LEN 2048
#define RAD   32

typedef unsigned short ushort_t;
typedef short bf16x8 __attribute__((ext_vector_type(8)));
typedef float f32x4  __attribute__((ext_vector_type(4)));
typedef unsigned short u16x4 __attribute__((ext_vector_type(4)));

__device__ __forceinline__ unsigned short f2bf(float f) {
  union { float f; unsigned int u; } v; v.f = f;
  unsigned int u = v.u;
  return (unsigned short)((u + 0x7FFFu + ((u >> 16) & 1u)) >> 16);
}
__device__ __forceinline__ float bf2f(unsigned short u) {
  union { unsigned int u; float f; } v; v.u = ((unsigned int)u) << 16;
  return v.f;
}
__device__ __forceinline__ bf16x8 cvt8(const float4* p) {
  float4 a = p[0], b = p[1];
  bf16x8 r;
  r[0] = (short)f2bf(a.x); r[1] = (short)f2bf(a.y);
  r[2] = (short)f2bf(a.z); r[3] = (short)f2bf(a.w);
  r[4] = (short)f2bf(b.x); r[5] = (short)f2bf(b.y);
  r[6] = (short)f2bf(b.z); r[7] = (short)f2bf(b.w);
  return r;
}

// ---- MFMA GEMM 1: C_bf16[M][N] = A_f32[M][K] @ B_f32[N][K]^T + bias ----
// 128x128 tile, BK=64, 4 waves (2x2), f32->bf16 convert during LDS staging.
// LDS rows padded to 72 bf16 (144B): aligned b128 reads, <=2-way conflicts.
__global__ __launch_bounds__(256) void gemm_bt_ff(
    const float* __restrict__ A, const float* __restrict__ Bm,
    const float* __restrict__ bias, ushort_t* __restrict__ C,
    int M, int N, int K) {
  const int bm = blockIdx.y * 128, bn = blockIdx.x * 128;
  __shared__ __align__(16) ushort_t As[128 * 72];
  __shared__ __align__(16) ushort_t Bs[128 * 72];
  const int tid = threadIdx.x;
  const int lane = tid & 63, wave = tid >> 6;
  const int wr = wave >> 1, wc = wave & 1;
  const int l15 = lane & 15, lg = lane >> 4;
  f32x4 acc[4][4] = {};

  for (int kt = 0; kt < K; kt += 64) {
    __syncthreads();
#pragma unroll
    for (int c = 0; c < 4; ++c) {
      int e = c * 256 + tid;              // 1024 chunks of 8 elems
      int row = e >> 3, k8 = (e & 7) << 3;
      *(bf16x8*)&As[row * 72 + k8] =
          cvt8((const float4*)(A + (size_t)(bm + row) * K + kt + k8));
      *(bf16x8*)&Bs[row * 72 + k8] =
          cvt8((const float4*)(Bm + (size_t)(bn + row) * K + kt + k8));
    }
    __syncthreads();

    bf16x8 af[2][4], bfr[2][4];
#pragma unroll
    for (int kg = 0; kg < 2; ++kg)
#pragma unroll
      for (int m = 0; m < 4; ++m) {
        af[kg][m]  = *(const bf16x8*)&As[(wr * 64 + m * 16 + l15) * 72 + kg * 32 + lg * 8];
        bfr[kg][m] = *(const bf16x8*)&Bs[(wc * 64 + m * 16 + l15) * 72 + kg * 32 + lg * 8];
      }
#pragma unroll
    for (int kg = 0; kg < 2; ++kg)
#pragma unroll
      for (int m = 0; m < 4; ++m)
#pragma unroll
        for (int n = 0; n < 4; ++n)
          acc[m][n] = __builtin_amdgcn_mfma_f32_16x16x32_bf16(
              af[kg][m], bfr[kg][n], acc[m][n], 0, 0, 0);
  }

  // C/D layout: col = lane&15, row = (lane>>4)*4 + j  [m89-verified]
#pragma unroll
  for (int m = 0; m < 4; ++m)
#pragma unroll
    for (int n = 0; n < 4; ++n) {
      int row0 = bm + wr * 64 + m * 16 + lg * 4;
      int col = bn + wc * 64 + n * 16 + l15;
      float bb = bias[col];
#pragma unroll
      for (int j = 0; j < 4; ++j)
        C[(size_t)(row0 + j) * N + col] = f2bf(acc[m][n][j] + bb);
    }
}

// ---- MFMA GEMM 2: C_f32[M][N] = A_bf16[M][K] @ B_f32[N][K]^T + bias ----
__global__ __launch_bounds__(256) void gemm_bt_bf(
    const ushort_t* __restrict__ A, const float* __restrict__ Bm,
    const float* __restrict__ bias, float* __restrict__ C,
    int M, int N, int K) {
  const int bm = blockIdx.y * 128, bn = blockIdx.x * 128;
  __shared__ __align__(16) ushort_t As[128 * 72];
  __shared__ __align__(16) ushort_t Bs[128 * 72];
  const int tid = threadIdx.x;
  const int lane = tid & 63, wave = tid >> 6;
  const int wr = wave >> 1, wc = wave & 1;
  const int l15 = lane & 15, lg = lane >> 4;
  f32x4 acc[4][4] = {};

  for (int kt = 0; kt < K; kt += 64) {
    __syncthreads();
#pragma unroll
    for (int c = 0; c < 4; ++c) {
      int e = c * 256 + tid;
      int row = e >> 3, k8 = (e & 7) << 3;
      *(bf16x8*)&As[row * 72 + k8] =
          *(const bf16x8*)(A + (size_t)(bm + row) * K + kt + k8);
      *(bf16x8*)&Bs[row * 72 + k8] =
          cvt8((const float4*)(Bm + (size_t)(bn + row) * K + kt + k8));
    }
    __syncthreads();

    bf16x8 af[2][4], bfr[2][4];
#pragma unroll
    for (int kg = 0; kg < 2; ++kg)
#pragma unroll
      for (int m = 0; m < 4; ++m) {
        af[kg][m]  = *(const bf16x8*)&As[(wr * 64 + m * 16 + l15) * 72 + kg * 32 + lg * 8];
        bfr[kg][m] = *(const bf16x8*)&Bs[(wc * 64 + m * 16 + l15) * 72 + kg * 32 + lg * 8];
      }
#pragma unroll
    for (int kg = 0; kg < 2; ++kg)
#pragma unroll
      for (int m = 0; m < 4; ++m)
#pragma unroll
        for (int n = 0; n < 4; ++n)
          acc[m][n] = __builtin_amdgcn_mfma_f32_16x16x32_bf16(
              af[kg][m], bfr[kg][n], acc[m][n], 0, 0, 0);
  }

#pragma unroll
  for (int m = 0; m < 4; ++m)
#pragma unroll
    for (int n = 0; n < 4; ++n) {
      int row0 = bm + wr * 64 + m * 16 + lg * 4;
      int col = bn + wc * 64 + n * 16 + l15;
      float bb = bias[col];
#pragma unroll
      for (int j = 0; j < 4; ++j)
        C[(size_t)(row0 + j) * N + col] = acc[m][n][j] + bb;
    }
}

// ---- fp32 local attention, register softmax (race-free, round-4 verified) ----
__global__ __launch_bounds__(256) void attn_kernel(
    const ushort_t* __restrict__ qkv, ushort_t* __restrict__ ctx) {
  const int b = blockIdx.z, h = blockIdx.y, t0 = blockIdx.x * 32;
  __shared__ float Kt[96][65];
  __shared__ float Vt[96][64];
  __shared__ float Qt[32][64];
  const int tid = threadIdx.x;
  const size_t baseBT = (size_t)b * T_LEN;

  // K/V staging: 96 rows x 16 chunks of 4 elems (8B-aligned u16x4 loads)
  for (int idx = tid; idx < 96 * 16; idx += 256) {
    int row = idx >> 4, c4 = (idx & 15) << 2;
    int t = t0 - RAD + row;
    if (t >= 0 && t < T_LEN) {
      const ushort_t* p = qkv + (baseBT + t) * 1536 + h * 64 + c4;
      u16x4 kq = *(const u16x4*)(p + 512);
      u16x4 vq = *(const u16x4*)(p + 1024);
#pragma unroll
      for (int j = 0; j < 4; ++j) { Kt[row][c4 + j] = bf2f(kq[j]); Vt[row][c4 + j] = bf2f(vq[j]); }
    } else {
#pragma unroll
      for (int j = 0; j < 4; ++j) { Kt[row][c4 + j] = 0.f; Vt[row][c4 + j] = 0.f; }
    }
  }
  for (int idx = tid; idx < 32 * 16; idx += 256) {
    int row = idx >> 4, c4 = (idx & 15) << 2;
    u16x4 qq = *(const u16x4*)(qkv + (baseBT + t0 + row) * 1536 + h * 64 + c4);
#pragma unroll
    for (int j = 0; j < 4; ++j) Qt[row][c4 + j] = bf2f(qq[j]);
  }
  __syncthreads();

  const int wave = tid >> 6, lane = tid & 63;
  for (int qi = 0; qi < 8; ++qi) {
    const int qrow = wave * 8 + qi;
    const int t = t0 + qrow;
    // phase 1: lane = window offset w (0..63); Kt stride 65 -> conflict-free
    float s = 0.f;
    for (int d = 0; d < 64; ++d)
      s += Qt[qrow][d] * Kt[qrow + lane][d];
    // w = 64 tail: lanes = d, butterfly reduce (ends wave-uniform)
    float p64 = Qt[qrow][lane] * Kt[qrow + 64][lane];
#pragma unroll
    for (int off = 32; off; off >>= 1) p64 += __shfl_xor(p64, off);

    int tw = t - RAD + lane;
    bool valid = (tw >= 0) && (tw < T_LEN);
    bool valid64 = (t + RAD) < T_LEN;
    float sv = valid ? s * 0.125f : -1e30f;
    float s64 = valid64 ? p64 * 0.125f : -1e30f;
    float mx = sv;
#pragma unroll
    for (int off = 32; off; off >>= 1) mx = fmaxf(mx, __shfl_xor(mx, off));
    mx = fmaxf(mx, s64);
    float e = valid ? expf(sv - mx) : 0.f;
    float esum = e;
#pragma unroll
    for (int off = 32; off; off >>= 1) esum += __shfl_xor(esum, off);
    float e64 = valid64 ? expf(s64 - mx) : 0.f;
    esum += e64;
    float inv = 1.0f / esum;
    float wv = e * inv;
    float tail = e64 * inv;

    // phase 2: lane = d; weights broadcast via shuffle (race-free)
    float c = 0.f;
#pragma unroll
    for (int w = 0; w < 64; ++w)
      c += __shfl(wv, w) * Vt[qrow + w][lane];
    c += tail * Vt[qrow + 64][lane];

    ctx[(baseBT + t) * 512 + h * 64 + lane] = f2bf(c);
  }
}

// ---------------- launch ----------------
extern "C" void kernel_launch(void* const* d_in, const int* in_sizes, int n_in,
                              void* d_out, int out_size, void* d_ws, size_t ws_size,
                              hipStream_t stream) {
  const float* x = nullptr; const float* Wqkv = nullptr; const float* bqkv = nullptr;
  const float* Wout = nullptr; const float* bout = nullptr;
  for (int i = 0; i < n_in; ++i) {
    switch (in_sizes[i]) {
      case 4194304: x    = (const float*)d_in[i]; break;  // 4*2048*512
      case 786432:  Wqkv = (const float*)d_in[i]; break;  // 1536*512
      case 1536:    bqkv = (const float*)d_in[i]; break;
      case 262144:  Wout = (const float*)d_in[i]; break;  // 512*512
      case 512:     bout = (const float*)d_in[i]; break;
      default: break;
    }
  }
  const size_t need_ws = ((size_t)8192 * 1536 + (size_t)8192 * 512) * 2;  // 32 MiB
  if (!x || !Wqkv || !bqkv || !Wout || !bout || ws_size < need_ws) return;
  float* out = (float*)d_out;

  ushort_t* qkvb = (ushort_t*)d_ws;                 // 8192*1536 bf16 = 24 MiB
  ushort_t* ctxb = qkvb + (size_t)8192 * 1536;      // 8192*512  bf16 =  8 MiB

  gemm_bt_ff<<<dim3(12, 64), dim3(256), 0, stream>>>(
      x, Wqkv, bqkv, qkvb, 8192, 1536, 512);

  attn_kernel<<<dim3(64, 8, 4), dim3(256), 0, stream>>>(qkvb, ctxb);

  gemm_bt_bf<<<dim3(4, 64), dim3(256), 0, stream>>>(
      ctxb, Wout, bout, out, 8192, 512, 512);
}

// Round 6
// 72.729 us; speedup vs baseline: 16.0071x; 2.2860x over previous
//
#include <hip/hip_runtime.h>
#include <stdint.h>

#define T_LEN 2048

typedef unsigned short ushort_t;
typedef short bf16x8 __attribute__((ext_vector_type(8)));
typedef float f32x4  __attribute__((ext_vector_type(4)));

__device__ __forceinline__ unsigned short f2bf(float f) {
  union { float f; unsigned int u; } v; v.f = f;
  unsigned int u = v.u;
  return (unsigned short)((u + 0x7FFFu + ((u >> 16) & 1u)) >> 16);
}
__device__ __forceinline__ float bf2f(unsigned short u) {
  union { unsigned int u; float f; } v; v.u = ((unsigned int)u) << 16;
  return v.f;
}
__device__ __forceinline__ bf16x8 cvt8(const float4* p) {
  float4 a = p[0], b = p[1];
  bf16x8 r;
  r[0] = (short)f2bf(a.x); r[1] = (short)f2bf(a.y);
  r[2] = (short)f2bf(a.z); r[3] = (short)f2bf(a.w);
  r[4] = (short)f2bf(b.x); r[5] = (short)f2bf(b.y);
  r[6] = (short)f2bf(b.z); r[7] = (short)f2bf(b.w);
  return r;
}

// ---- MFMA GEMM 1: C_bf16[M][N] = A_f32[M][K] @ B_f32[N][K]^T + bias ----
__global__ __launch_bounds__(256) void gemm_bt_ff(
    const float* __restrict__ A, const float* __restrict__ Bm,
    const float* __restrict__ bias, ushort_t* __restrict__ C,
    int M, int N, int K) {
  const int bm = blockIdx.y * 128, bn = blockIdx.x * 128;
  __shared__ __align__(16) ushort_t As[128 * 72];
  __shared__ __align__(16) ushort_t Bs[128 * 72];
  const int tid = threadIdx.x;
  const int lane = tid & 63, wave = tid >> 6;
  const int wr = wave >> 1, wc = wave & 1;
  const int l15 = lane & 15, lg = lane >> 4;
  f32x4 acc[4][4] = {};

  for (int kt = 0; kt < K; kt += 64) {
    __syncthreads();
#pragma unroll
    for (int c = 0; c < 4; ++c) {
      int e = c * 256 + tid;
      int row = e >> 3, k8 = (e & 7) << 3;
      *(bf16x8*)&As[row * 72 + k8] =
          cvt8((const float4*)(A + (size_t)(bm + row) * K + kt + k8));
      *(bf16x8*)&Bs[row * 72 + k8] =
          cvt8((const float4*)(Bm + (size_t)(bn + row) * K + kt + k8));
    }
    __syncthreads();

    bf16x8 af[2][4], bfr[2][4];
#pragma unroll
    for (int kg = 0; kg < 2; ++kg)
#pragma unroll
      for (int m = 0; m < 4; ++m) {
        af[kg][m]  = *(const bf16x8*)&As[(wr * 64 + m * 16 + l15) * 72 + kg * 32 + lg * 8];
        bfr[kg][m] = *(const bf16x8*)&Bs[(wc * 64 + m * 16 + l15) * 72 + kg * 32 + lg * 8];
      }
#pragma unroll
    for (int kg = 0; kg < 2; ++kg)
#pragma unroll
      for (int m = 0; m < 4; ++m)
#pragma unroll
        for (int n = 0; n < 4; ++n)
          acc[m][n] = __builtin_amdgcn_mfma_f32_16x16x32_bf16(
              af[kg][m], bfr[kg][n], acc[m][n], 0, 0, 0);
  }

#pragma unroll
  for (int m = 0; m < 4; ++m)
#pragma unroll
    for (int n = 0; n < 4; ++n) {
      int row0 = bm + wr * 64 + m * 16 + lg * 4;
      int col = bn + wc * 64 + n * 16 + l15;
      float bb = bias[col];
#pragma unroll
      for (int j = 0; j < 4; ++j)
        C[(size_t)(row0 + j) * N + col] = f2bf(acc[m][n][j] + bb);
    }
}

// ---- MFMA GEMM 2: C_f32[M][N] = A_bf16[M][K] @ B_f32[N][K]^T + bias ----
__global__ __launch_bounds__(256) void gemm_bt_bf(
    const ushort_t* __restrict__ A, const float* __restrict__ Bm,
    const float* __restrict__ bias, float* __restrict__ C,
    int M, int N, int K) {
  const int bm = blockIdx.y * 128, bn = blockIdx.x * 128;
  __shared__ __align__(16) ushort_t As[128 * 72];
  __shared__ __align__(16) ushort_t Bs[128 * 72];
  const int tid = threadIdx.x;
  const int lane = tid & 63, wave = tid >> 6;
  const int wr = wave >> 1, wc = wave & 1;
  const int l15 = lane & 15, lg = lane >> 4;
  f32x4 acc[4][4] = {};

  for (int kt = 0; kt < K; kt += 64) {
    __syncthreads();
#pragma unroll
    for (int c = 0; c < 4; ++c) {
      int e = c * 256 + tid;
      int row = e >> 3, k8 = (e & 7) << 3;
      *(bf16x8*)&As[row * 72 + k8] =
          *(const bf16x8*)(A + (size_t)(bm + row) * K + kt + k8);
      *(bf16x8*)&Bs[row * 72 + k8] =
          cvt8((const float4*)(Bm + (size_t)(bn + row) * K + kt + k8));
    }
    __syncthreads();

    bf16x8 af[2][4], bfr[2][4];
#pragma unroll
    for (int kg = 0; kg < 2; ++kg)
#pragma unroll
      for (int m = 0; m < 4; ++m) {
        af[kg][m]  = *(const bf16x8*)&As[(wr * 64 + m * 16 + l15) * 72 + kg * 32 + lg * 8];
        bfr[kg][m] = *(const bf16x8*)&Bs[(wc * 64 + m * 16 + l15) * 72 + kg * 32 + lg * 8];
      }
#pragma unroll
    for (int kg = 0; kg < 2; ++kg)
#pragma unroll
      for (int m = 0; m < 4; ++m)
#pragma unroll
        for (int n = 0; n < 4; ++n)
          acc[m][n] = __builtin_amdgcn_mfma_f32_16x16x32_bf16(
              af[kg][m], bfr[kg][n], acc[m][n], 0, 0, 0);
  }

#pragma unroll
  for (int m = 0; m < 4; ++m)
#pragma unroll
    for (int n = 0; n < 4; ++n) {
      int row0 = bm + wr * 64 + m * 16 + lg * 4;
      int col = bn + wc * 64 + n * 16 + l15;
      float bb = bias[col];
#pragma unroll
      for (int j = 0; j < 4; ++j)
        C[(size_t)(row0 + j) * N + col] = acc[m][n][j] + bb;
    }
}

// ---- MFMA local attention ----
// Block: 4 waves = 128 queries of one (b,h). Keys staged [tB-32, tB+159].
// Per wave: S[32][96] via 24 MFMA, in-register softmax (16-lane shfl reduces),
// P -> per-wave LDS slab (barrier-fenced), ctx[32][64] = P @ V^T via 24 MFMA.
__global__ __launch_bounds__(256) void attn_mfma(
    const ushort_t* __restrict__ qkv, ushort_t* __restrict__ ctx) {
  const int b = blockIdx.z, h = blockIdx.y, tB = blockIdx.x * 128;
  __shared__ __align__(16) ushort_t Ks[192][72];    // K rows [key][d], 27.6 KB
  __shared__ __align__(16) ushort_t Vts[64][200];   // V^T [d][key],   25.6 KB
  __shared__ __align__(16) ushort_t Ps[4][32][104]; // per-wave P,     26.6 KB
  const int tid = threadIdx.x;
  const int wave = tid >> 6, lane = tid & 63;
  const int l15 = lane & 15, lg = lane >> 4;
  const size_t baseBT = (size_t)b * T_LEN;

  // stage K: coalesced rows (8 threads x 16B per key row)
  for (int idx = tid; idx < 1536; idx += 256) {
    int key = idx >> 3, d8 = (idx & 7) << 3;
    int t = tB - 32 + key;
    bf16x8 kv = {};
    if (t >= 0 && t < T_LEN)
      kv = *(const bf16x8*)(qkv + (baseBT + t) * 1536 + 512 + h * 64 + d8);
    *(bf16x8*)&Ks[key][d8] = kv;
  }
  // stage V transposed: key-major mapping -> consecutive lanes write
  // consecutive keys (2B apart) => <=2 lanes/bank, conflict-free
  for (int idx = tid; idx < 1536; idx += 256) {
    int d8 = (idx / 192) << 3, key = idx % 192;
    int t = tB - 32 + key;
    bf16x8 vv = {};
    if (t >= 0 && t < T_LEN)
      vv = *(const bf16x8*)(qkv + (baseBT + t) * 1536 + 1024 + h * 64 + d8);
#pragma unroll
    for (int j = 0; j < 8; ++j) Vts[d8 + j][key] = (ushort_t)vv[j];
  }
  // Q fragments direct from global
  bf16x8 qf[2][2];
#pragma unroll
  for (int m = 0; m < 2; ++m)
#pragma unroll
    for (int kg = 0; kg < 2; ++kg) {
      int tq = tB + wave * 32 + m * 16 + l15;
      qf[m][kg] = *(const bf16x8*)(qkv + (baseBT + tq) * 1536 + h * 64 + kg * 32 + lg * 8);
    }
  __syncthreads();

  // QK^T: S[q 32][key 96] for this wave (wave's key 0 = block key wave*32)
  f32x4 acc[2][6] = {};
#pragma unroll
  for (int n = 0; n < 6; ++n) {
    int keyr = wave * 32 + n * 16 + l15;
#pragma unroll
    for (int kg = 0; kg < 2; ++kg) {
      bf16x8 kf = *(const bf16x8*)&Ks[keyr][kg * 32 + lg * 8];
#pragma unroll
      for (int m = 0; m < 2; ++m)
        acc[m][n] = __builtin_amdgcn_mfma_f32_16x16x32_bf16(
            qf[m][kg], kf, acc[m][n], 0, 0, 0);
    }
  }

  // softmax per row; D layout: row = m*16 + lg*4 + jj, col = n*16 + l15
  ushort_t* Pw = &Ps[wave][0][0];
#pragma unroll
  for (int m = 0; m < 2; ++m) {
#pragma unroll
    for (int jj = 0; jj < 4; ++jj) {
      int ql = m * 16 + lg * 4 + jj;
      float sv[6]; bool ok[6];
      float mx = -1e30f;
#pragma unroll
      for (int n = 0; n < 6; ++n) {
        int kl = n * 16 + l15;
        int tk = tB + wave * 32 - 32 + kl;
        int dd = kl - ql;
        ok[n] = (dd >= 0) && (dd <= 64) && (tk >= 0) && (tk < T_LEN);
        sv[n] = ok[n] ? acc[m][n][jj] * 0.125f : -1e30f;
        mx = fmaxf(mx, sv[n]);
      }
#pragma unroll
      for (int off = 8; off; off >>= 1) mx = fmaxf(mx, __shfl_xor(mx, off));
      float es[6], sum = 0.f;
#pragma unroll
      for (int n = 0; n < 6; ++n) { es[n] = ok[n] ? __expf(sv[n] - mx) : 0.f; sum += es[n]; }
#pragma unroll
      for (int off = 8; off; off >>= 1) sum += __shfl_xor(sum, off);
      float inv = 1.0f / sum;
#pragma unroll
      for (int n = 0; n < 6; ++n)
        Pw[ql * 104 + n * 16 + l15] = f2bf(es[n] * inv);
    }
  }
  __syncthreads();  // fence Ps writes -> reads (and no same-wave-RAW gamble)

  // PV: ctx[32 q][64 d] = P[32][96] @ Vt[64][96]^T  (both row-major [rows][k])
  f32x4 acc2[2][4] = {};
#pragma unroll
  for (int ks = 0; ks < 3; ++ks) {
    bf16x8 pa[2], vb[4];
#pragma unroll
    for (int m = 0; m < 2; ++m)
      pa[m] = *(const bf16x8*)&Pw[(m * 16 + l15) * 104 + ks * 32 + lg * 8];
#pragma unroll
    for (int nn = 0; nn < 4; ++nn)
      vb[nn] = *(const bf16x8*)&Vts[nn * 16 + l15][wave * 32 + ks * 32 + lg * 8];
#pragma unroll
    for (int m = 0; m < 2; ++m)
#pragma unroll
      for (int nn = 0; nn < 4; ++nn)
        acc2[m][nn] = __builtin_amdgcn_mfma_f32_16x16x32_bf16(
            pa[m], vb[nn], acc2[m][nn], 0, 0, 0);
  }

#pragma unroll
  for (int m = 0; m < 2; ++m)
#pragma unroll
    for (int nn = 0; nn < 4; ++nn) {
      int col = h * 64 + nn * 16 + l15;
#pragma unroll
      for (int jj = 0; jj < 4; ++jj) {
        int tq = tB + wave * 32 + m * 16 + lg * 4 + jj;
        ctx[(baseBT + tq) * 512 + col] = f2bf(acc2[m][nn][jj]);
      }
    }
}

// ---------------- launch ----------------
extern "C" void kernel_launch(void* const* d_in, const int* in_sizes, int n_in,
                              void* d_out, int out_size, void* d_ws, size_t ws_size,
                              hipStream_t stream) {
  const float* x = nullptr; const float* Wqkv = nullptr; const float* bqkv = nullptr;
  const float* Wout = nullptr; const float* bout = nullptr;
  for (int i = 0; i < n_in; ++i) {
    switch (in_sizes[i]) {
      case 4194304: x    = (const float*)d_in[i]; break;  // 4*2048*512
      case 786432:  Wqkv = (const float*)d_in[i]; break;  // 1536*512
      case 1536:    bqkv = (const float*)d_in[i]; break;
      case 262144:  Wout = (const float*)d_in[i]; break;  // 512*512
      case 512:     bout = (const float*)d_in[i]; break;
      default: break;
    }
  }
  const size_t need_ws = ((size_t)8192 * 1536 + (size_t)8192 * 512) * 2;  // 32 MiB
  if (!x || !Wqkv || !bqkv || !Wout || !bout || ws_size < need_ws) return;
  float* out = (float*)d_out;

  ushort_t* qkvb = (ushort_t*)d_ws;                 // 24 MiB
  ushort_t* ctxb = qkvb + (size_t)8192 * 1536;      //  8 MiB

  gemm_bt_ff<<<dim3(12, 64), dim3(256), 0, stream>>>(
      x, Wqkv, bqkv, qkvb, 8192, 1536, 512);

  attn_mfma<<<dim3(16, 8, 4), dim3(256), 0, stream>>>(qkvb, ctxb);

  gemm_bt_bf<<<dim3(4, 64), dim3(256), 0, stream>>>(
      ctxb, Wout, bout, out, 8192, 512, 512);
}